// Round 1
// baseline (694.984 us; speedup 1.0000x reference)
//
#include <hip/hip_runtime.h>
#include <math.h>

#define QMAXF 32767.0f

__device__ __forceinline__ float clampf(float v, float lo, float hi) {
    return fminf(fmaxf(v, lo), hi);
}
// symmetric fake-quant: returns the integer code as float (clip(rint(x/s)))
__device__ __forceinline__ float fq_code(float x, float s) {
    return clampf(rintf(x / s), -QMAXF, QMAXF);
}
// h-GELU integer code k (output value = k * 2^-shift)
__device__ __forceinline__ float hgelu_code(float y, float sc, float three, float six) {
    float xi    = clampf(rintf(y * sc), -32768.f, 32767.f);
    float slope = rintf(xi * 218.0f / 128.0f);   // exact in fp32 up to rint
    float gate  = clampf(slope + three, 0.f, six);
    return clampf(rintf(xi * gate / six), -QMAXF, QMAXF);
}

// ---------------- weight prep: per-tensor scale + quantize + layout transpose ----------------
__device__ float block_scale(const float* w, int n, float* red) {
    float m = 0.f;
    for (int i = threadIdx.x; i < n; i += blockDim.x) m = fmaxf(m, fabsf(w[i]));
    red[threadIdx.x] = m; __syncthreads();
    for (int s = blockDim.x >> 1; s > 0; s >>= 1) {
        if ((int)threadIdx.x < s) red[threadIdx.x] = fmaxf(red[threadIdx.x], red[threadIdx.x + s]);
        __syncthreads();
    }
    float r = red[0]; __syncthreads();
    return fmaxf(r / QMAXF, 1e-8f);
}

__global__ void prep_kernel(const float* __restrict__ w1, const float* __restrict__ w2,
                            const float* __restrict__ w3, const float* __restrict__ wfc,
                            float* __restrict__ wq1, float* __restrict__ wq2,
                            float* __restrict__ wq3, float* __restrict__ wqfc) {
    __shared__ float red[256];
    float s = block_scale(w1, 144, red);   // [16][1][3][3] -> [ky*3+kx][16]
    for (int i = threadIdx.x; i < 144; i += 256) {
        int co = i / 9, r = i % 9;
        wq1[r * 16 + co] = fq_code(w1[i], s) * s;
    }
    __syncthreads();
    s = block_scale(w2, 2304, red);        // [16][16][3][3] -> [cin*9+r][16]
    for (int i = threadIdx.x; i < 2304; i += 256) {
        int co = i / 144, rem = i % 144, cin = rem / 9, r = rem % 9;
        wq2[(cin * 9 + r) * 16 + co] = fq_code(w2[i], s) * s;
    }
    __syncthreads();
    s = block_scale(w3, 2304, red);
    for (int i = threadIdx.x; i < 2304; i += 256) {
        int co = i / 144, rem = i % 144, cin = rem / 9, r = rem % 9;
        wq3[(cin * 9 + r) * 16 + co] = fq_code(w3[i], s) * s;
    }
    __syncthreads();
    s = block_scale(wfc, 160, red);        // keep [o][i]
    for (int i = threadIdx.x; i < 160; i += 256) wqfc[i] = fq_code(wfc[i], s) * s;
}

// ---------------- conv1: 1->16 ch, fused hgelu + next-layer quantize ----------------
__global__ __launch_bounds__(448) void conv1_kernel(const float* __restrict__ x,
        const float* __restrict__ wq, const float* __restrict__ bias,
        const float* __restrict__ asc, const float* __restrict__ shf,
        short* __restrict__ out) {
    const int bid = blockIdx.x;
    const int b = bid / 28, rt = bid % 28, r0 = rt * 8;
    const int tid = threadIdx.x;
    __shared__ alignas(16) short lx[10][224];
    __shared__ alignas(16) float lw[144];
    __shared__ float lb[16];
    const float a0 = asc[0], a1 = asc[1];
    const float sh = clampf(rintf(shf[0]), 4.f, 12.f);
    const float sc = exp2f(sh), osc = exp2f(-sh);
    const float three = 3.f * sc, six = 6.f * sc;
    const float* xb = x + (size_t)b * 50176;
    for (int i = tid; i < 2240; i += 448) {
        int r = i / 224, c = i - r * 224, sr = r0 - 1 + r;
        float v = (sr >= 0 && sr < 224) ? xb[sr * 224 + c] : 0.f;
        lx[r][c] = (short)fq_code(v, a0);
    }
    for (int i = tid; i < 144; i += 448) lw[i] = wq[i];
    if (tid < 16) lb[tid] = bias[tid];
    __syncthreads();
    const int myrow = tid / 56, p0 = (tid - myrow * 56) * 4;
    float acc[4][16];
#pragma unroll
    for (int px = 0; px < 4; px++)
#pragma unroll
        for (int co = 0; co < 16; co++) acc[px][co] = 0.f;
#pragma unroll
    for (int ky = 0; ky < 3; ky++) {
        const short* rp = &lx[myrow + ky][0];
        float xf[6];
        short4 v = *(const short4*)(rp + p0);
        xf[1] = (float)v.x * a0; xf[2] = (float)v.y * a0;
        xf[3] = (float)v.z * a0; xf[4] = (float)v.w * a0;
        xf[0] = (p0 > 0)   ? (float)rp[p0 - 1] * a0 : 0.f;
        xf[5] = (p0 < 220) ? (float)rp[p0 + 4] * a0 : 0.f;
#pragma unroll
        for (int kx = 0; kx < 3; kx++) {
            const float* wp = &lw[(ky * 3 + kx) * 16];
#pragma unroll
            for (int px = 0; px < 4; px++) {
                float xv = xf[px + kx];
#pragma unroll
                for (int co = 0; co < 16; co++) acc[px][co] = fmaf(xv, wp[co], acc[px][co]);
            }
        }
    }
    const int orow = r0 + myrow;
#pragma unroll
    for (int co = 0; co < 16; co++) {
        float bb = lb[co];
        short4 st;
        float k0 = hgelu_code(acc[0][co] + bb, sc, three, six);
        float k1 = hgelu_code(acc[1][co] + bb, sc, three, six);
        float k2 = hgelu_code(acc[2][co] + bb, sc, three, six);
        float k3 = hgelu_code(acc[3][co] + bb, sc, three, six);
        st.x = (short)fq_code(k0 * osc, a1);
        st.y = (short)fq_code(k1 * osc, a1);
        st.z = (short)fq_code(k2 * osc, a1);
        st.w = (short)fq_code(k3 * osc, a1);
        *(short4*)(out + (((size_t)b * 16 + co) * 224 + orow) * 224 + p0) = st;
    }
}

// ---------------- conv2/conv3: 16->16 ch ----------------
// POOL=false: fused hgelu + requant -> int16 codes out
// POOL=true:  fused hgelu + deterministic partial pooling sums
template <bool POOL>
__global__ __launch_bounds__(448) void conv16_kernel(const short* __restrict__ in,
        const float* __restrict__ wq, const float* __restrict__ bias,
        const float* __restrict__ asc, const float* __restrict__ shf,
        short* __restrict__ out, float* __restrict__ partial, int aidx, int sidx) {
    const int bid = blockIdx.x;
    const int b = bid / 28, rt = bid % 28, r0 = rt * 8;
    const int tid = threadIdx.x;
    __shared__ alignas(16) short lx[10][16][224];  // 71680 B
    __shared__ alignas(16) float lw[2304];         //  9216 B
    __shared__ float lb[16];
    __shared__ float lred[7][16];
    const float ain = asc[aidx];
    const float anext = asc[aidx + 1];
    const float sh = clampf(rintf(shf[sidx]), 4.f, 12.f);
    const float sc = exp2f(sh), osc = exp2f(-sh);
    const float three = 3.f * sc, six = 6.f * sc;
    // stage 10 rows x 16 cin x 224 cols of int16 codes (vectorized 16B)
    {
        const int cin = tid / 28, g = tid - cin * 28, c0 = g * 8;
        const size_t base = ((size_t)b * 16 + cin) * 224;
#pragma unroll
        for (int it = 0; it < 10; it++) {
            int sr = r0 - 1 + it;
            uint4 v;
            if (sr >= 0 && sr < 224) v = *(const uint4*)(in + (base + sr) * 224 + c0);
            else                     v = make_uint4(0u, 0u, 0u, 0u);
            *(uint4*)(&lx[it][cin][c0]) = v;
        }
    }
    for (int i = tid; i < 2304; i += 448) lw[i] = wq[i];
    if (tid < 16) lb[tid] = bias[tid];
    __syncthreads();
    const int myrow = tid / 56, p0 = (tid - myrow * 56) * 4;
    float acc[4][16];
#pragma unroll
    for (int px = 0; px < 4; px++)
#pragma unroll
        for (int co = 0; co < 16; co++) acc[px][co] = 0.f;
#pragma unroll 1
    for (int cin = 0; cin < 16; cin++) {
#pragma unroll
        for (int ky = 0; ky < 3; ky++) {
            const short* rp = &lx[myrow + ky][cin][0];
            float xf[6];
            short4 v = *(const short4*)(rp + p0);
            xf[1] = (float)v.x * ain; xf[2] = (float)v.y * ain;
            xf[3] = (float)v.z * ain; xf[4] = (float)v.w * ain;
            xf[0] = (p0 > 0)   ? (float)rp[p0 - 1] * ain : 0.f;
            xf[5] = (p0 < 220) ? (float)rp[p0 + 4] * ain : 0.f;
#pragma unroll
            for (int kx = 0; kx < 3; kx++) {
                const float* wp = &lw[((cin * 3 + ky) * 3 + kx) * 16];
#pragma unroll
                for (int px = 0; px < 4; px++) {
                    float xv = xf[px + kx];
#pragma unroll
                    for (int co = 0; co < 16; co++) acc[px][co] = fmaf(xv, wp[co], acc[px][co]);
                }
            }
        }
    }
    const int orow = r0 + myrow;
    if (!POOL) {
#pragma unroll
        for (int co = 0; co < 16; co++) {
            float bb = lb[co];
            short4 st;
            float k0 = hgelu_code(acc[0][co] + bb, sc, three, six);
            float k1 = hgelu_code(acc[1][co] + bb, sc, three, six);
            float k2 = hgelu_code(acc[2][co] + bb, sc, three, six);
            float k3 = hgelu_code(acc[3][co] + bb, sc, three, six);
            st.x = (short)fq_code(k0 * osc, anext);
            st.y = (short)fq_code(k1 * osc, anext);
            st.z = (short)fq_code(k2 * osc, anext);
            st.w = (short)fq_code(k3 * osc, anext);
            *(short4*)(out + (((size_t)b * 16 + co) * 224 + orow) * 224 + p0) = st;
        }
    } else {
        const int lane = tid & 63, wv = tid >> 6;
#pragma unroll
        for (int co = 0; co < 16; co++) {
            float bb = lb[co];
            float s = 0.f;
#pragma unroll
            for (int px = 0; px < 4; px++) {
                float k = hgelu_code(acc[px][co] + bb, sc, three, six);
                s += k * osc;
            }
#pragma unroll
            for (int o = 32; o > 0; o >>= 1) s += __shfl_xor(s, o);
            if (lane == 0) lred[wv][co] = s;
        }
        __syncthreads();
        if (tid < 16) {
            float t = 0.f;
#pragma unroll
            for (int w = 0; w < 7; w++) t += lred[w][tid];
            partial[((size_t)b * 28 + rt) * 16 + tid] = t;
        }
    }
}

// ---------------- pool-reduce + quantized FC ----------------
__global__ __launch_bounds__(1024) void fc_kernel(const float* __restrict__ partial,
        const float* __restrict__ wq, const float* __restrict__ fb,
        const float* __restrict__ asc, float* __restrict__ out) {
    __shared__ float xq[64][16];
    const int t = threadIdx.x;
    const float a3 = asc[3];
    {
        int b = t >> 4, c = t & 15;
        const float* p = partial + ((size_t)b * 28) * 16 + c;
        float s = 0.f;
        for (int i = 0; i < 28; i++) s += p[i * 16];
        float pooled = s / 50176.0f;
        xq[b][c] = fq_code(pooled, a3) * a3;
    }
    __syncthreads();
    if (t < 640) {
        int b = t / 10, o = t - (t / 10) * 10;
        float s = 0.f;
#pragma unroll
        for (int c = 0; c < 16; c++) s += xq[b][c] * wq[o * 16 + c];
        out[t] = s + fb[o];
    }
}

extern "C" void kernel_launch(void* const* d_in, const int* in_sizes, int n_in,
                              void* d_out, int out_size, void* d_ws, size_t ws_size,
                              hipStream_t stream) {
    const float* x   = (const float*)d_in[0];
    const float* c1w = (const float*)d_in[1];
    const float* c1b = (const float*)d_in[2];
    const float* c2w = (const float*)d_in[3];
    const float* c2b = (const float*)d_in[4];
    const float* c3w = (const float*)d_in[5];
    const float* c3b = (const float*)d_in[6];
    const float* fcw = (const float*)d_in[7];
    const float* fcb = (const float*)d_in[8];
    const float* asc = (const float*)d_in[9];
    const float* shf = (const float*)d_in[10];

    char* ws = (char*)d_ws;
    size_t off = 0;
    auto alloc = [&](size_t bytes) -> void* {
        void* p = ws + off;
        off = (off + bytes + 255) & ~(size_t)255;
        return p;
    };
    float* wq1     = (float*)alloc(144 * 4);
    float* wq2     = (float*)alloc(2304 * 4);
    float* wq3     = (float*)alloc(2304 * 4);
    float* wqfc    = (float*)alloc(160 * 4);
    float* partial = (float*)alloc(64 * 28 * 16 * 4);
    short* actA    = (short*)alloc(51380224ull * 2);
    short* actB    = (short*)alloc(51380224ull * 2);

    prep_kernel<<<1, 256, 0, stream>>>(c1w, c2w, c3w, fcw, wq1, wq2, wq3, wqfc);
    conv1_kernel<<<1792, 448, 0, stream>>>(x, wq1, c1b, asc, shf, actA);
    conv16_kernel<false><<<1792, 448, 0, stream>>>(actA, wq2, c2b, asc, shf, actB, nullptr, 1, 1);
    conv16_kernel<true ><<<1792, 448, 0, stream>>>(actB, wq3, c3b, asc, shf, nullptr, partial, 2, 2);
    fc_kernel<<<1, 1024, 0, stream>>>(partial, wqfc, fcb, asc, (float*)d_out);
}

// Round 2
// 603.827 us; speedup vs baseline: 1.1510x; 1.1510x over previous
//
#include <hip/hip_runtime.h>
#include <math.h>

#define QMAXF 32767.0f

__device__ __forceinline__ float clampf(float v, float lo, float hi) {
    return fminf(fmaxf(v, lo), hi);
}
// symmetric fake-quant: returns the integer code as float (clip(rint(x/s)))
__device__ __forceinline__ float fq_code(float x, float s) {
    return clampf(rintf(x / s), -QMAXF, QMAXF);
}
// h-GELU integer code k (output value = k * 2^-shift)
__device__ __forceinline__ float hgelu_code(float y, float sc, float three, float six) {
    float xi    = clampf(rintf(y * sc), -32768.f, 32767.f);
    float slope = rintf(xi * 218.0f / 128.0f);   // exact in fp32 up to rint
    float gate  = clampf(slope + three, 0.f, six);
    return clampf(rintf(xi * gate / six), -QMAXF, QMAXF);
}

// ---------------- weight prep: per-tensor scale + quantize + layout transpose ----------------
__device__ float block_scale(const float* w, int n, float* red) {
    float m = 0.f;
    for (int i = threadIdx.x; i < n; i += blockDim.x) m = fmaxf(m, fabsf(w[i]));
    red[threadIdx.x] = m; __syncthreads();
    for (int s = blockDim.x >> 1; s > 0; s >>= 1) {
        if ((int)threadIdx.x < s) red[threadIdx.x] = fmaxf(red[threadIdx.x], red[threadIdx.x + s]);
        __syncthreads();
    }
    float r = red[0]; __syncthreads();
    return fmaxf(r / QMAXF, 1e-8f);
}

__global__ void prep_kernel(const float* __restrict__ w1, const float* __restrict__ w2,
                            const float* __restrict__ w3, const float* __restrict__ wfc,
                            float* __restrict__ wq1, float* __restrict__ wq2,
                            float* __restrict__ wq3, float* __restrict__ wqfc) {
    __shared__ float red[256];
    float s = block_scale(w1, 144, red);   // [16][1][3][3] -> [ky*3+kx][16]
    for (int i = threadIdx.x; i < 144; i += 256) {
        int co = i / 9, r = i % 9;
        wq1[r * 16 + co] = fq_code(w1[i], s) * s;
    }
    __syncthreads();
    s = block_scale(w2, 2304, red);        // [16][16][3][3] -> [cin*9+r][16]
    for (int i = threadIdx.x; i < 2304; i += 256) {
        int co = i / 144, rem = i % 144, cin = rem / 9, r = rem % 9;
        wq2[(cin * 9 + r) * 16 + co] = fq_code(w2[i], s) * s;
    }
    __syncthreads();
    s = block_scale(w3, 2304, red);
    for (int i = threadIdx.x; i < 2304; i += 256) {
        int co = i / 144, rem = i % 144, cin = rem / 9, r = rem % 9;
        wq3[(cin * 9 + r) * 16 + co] = fq_code(w3[i], s) * s;
    }
    __syncthreads();
    s = block_scale(wfc, 160, red);        // keep [o][i]
    for (int i = threadIdx.x; i < 160; i += 256) wqfc[i] = fq_code(wfc[i], s) * s;
}

// ---------------- conv1: 1->16 ch, fused hgelu + next-layer quantize ----------------
__global__ __launch_bounds__(448) void conv1_kernel(const float* __restrict__ x,
        const float* __restrict__ wq, const float* __restrict__ bias,
        const float* __restrict__ asc, const float* __restrict__ shf,
        short* __restrict__ out) {
    const int bid = blockIdx.x;
    const int b = bid / 28, rt = bid % 28, r0 = rt * 8;
    const int tid = threadIdx.x;
    __shared__ alignas(16) short lx[10][224];
    __shared__ alignas(16) float lw[144];
    __shared__ float lb[16];
    const float a0 = asc[0], a1 = asc[1];
    const float sh = clampf(rintf(shf[0]), 4.f, 12.f);
    const float sc = exp2f(sh), osc = exp2f(-sh);
    const float three = 3.f * sc, six = 6.f * sc;
    const float* xb = x + (size_t)b * 50176;
    for (int i = tid; i < 2240; i += 448) {
        int r = i / 224, c = i - r * 224, sr = r0 - 1 + r;
        float v = (sr >= 0 && sr < 224) ? xb[sr * 224 + c] : 0.f;
        lx[r][c] = (short)fq_code(v, a0);
    }
    for (int i = tid; i < 144; i += 448) lw[i] = wq[i];
    if (tid < 16) lb[tid] = bias[tid];
    __syncthreads();
    const int myrow = tid / 56, p0 = (tid - myrow * 56) * 4;
    float acc[4][16];
#pragma unroll
    for (int px = 0; px < 4; px++)
#pragma unroll
        for (int co = 0; co < 16; co++) acc[px][co] = 0.f;
#pragma unroll
    for (int ky = 0; ky < 3; ky++) {
        const short* rp = &lx[myrow + ky][0];
        float xf[6];
        short4 v = *(const short4*)(rp + p0);
        xf[1] = (float)v.x * a0; xf[2] = (float)v.y * a0;
        xf[3] = (float)v.z * a0; xf[4] = (float)v.w * a0;
        xf[0] = (p0 > 0)   ? (float)rp[p0 - 1] * a0 : 0.f;
        xf[5] = (p0 < 220) ? (float)rp[p0 + 4] * a0 : 0.f;
#pragma unroll
        for (int kx = 0; kx < 3; kx++) {
            const float* wp = &lw[(ky * 3 + kx) * 16];
#pragma unroll
            for (int px = 0; px < 4; px++) {
                float xv = xf[px + kx];
#pragma unroll
                for (int co = 0; co < 16; co++) acc[px][co] = fmaf(xv, wp[co], acc[px][co]);
            }
        }
    }
    const int orow = r0 + myrow;
#pragma unroll
    for (int co = 0; co < 16; co++) {
        float bb = lb[co];
        short4 st;
        float k0 = hgelu_code(acc[0][co] + bb, sc, three, six);
        float k1 = hgelu_code(acc[1][co] + bb, sc, three, six);
        float k2 = hgelu_code(acc[2][co] + bb, sc, three, six);
        float k3 = hgelu_code(acc[3][co] + bb, sc, three, six);
        st.x = (short)fq_code(k0 * osc, a1);
        st.y = (short)fq_code(k1 * osc, a1);
        st.z = (short)fq_code(k2 * osc, a1);
        st.w = (short)fq_code(k3 * osc, a1);
        *(short4*)(out + (((size_t)b * 16 + co) * 224 + orow) * 224 + p0) = st;
    }
}

// ---------------- conv2/conv3: 16->16 ch, retiled 8px x 4co per thread ----------------
// LDS x layout: per (cin,row): 232-short rows, x[c] stored at col c+8, cols 0..7 zero,
// cols 232.. covered by next row's left pad (tail +8 at end). All reads aligned b64/b128.
template <bool POOL>
__global__ __launch_bounds__(448, 4) void conv16_kernel(const short* __restrict__ in,
        const float* __restrict__ wq, const float* __restrict__ bias,
        const float* __restrict__ asc, const float* __restrict__ shf,
        short* __restrict__ out, float* __restrict__ partial, int aidx, int sidx) {
    const int bid = blockIdx.x;
    const int b = bid / 56, rt = bid % 56, r0 = rt * 4;
    const int tid = threadIdx.x;
    __shared__ alignas(16) short ls[16 * 6 * 232 + 8];   // 44,576 B
    __shared__ alignas(16) float lw[2304];               //  9,216 B (reused as pool scratch)
    __shared__ float lb[16];
    __shared__ float lred[4][16];
    const float ain = asc[aidx];
    const float anext = asc[aidx + 1];
    const float sh = clampf(rintf(shf[sidx]), 4.f, 12.f);
    const float sc = exp2f(sh), osc = exp2f(-sh);
    const float three = 3.f * sc, six = 6.f * sc;
    // ---- stage: 16 cin x 6 rows x 30 uint4 (240 shorts incl. pads) ----
#pragma unroll
    for (int k = 0; k < 7; k++) {
        int i = tid + k * 448;
        if (i < 2880) {
            int cin = i / 180, rem = i - cin * 180, r = rem / 30, g = rem - r * 30;
            int gr = r0 - 1 + r, c0 = 8 * g - 8;
            uint4 v = make_uint4(0u, 0u, 0u, 0u);
            if ((unsigned)gr < 224u && g >= 1 && g <= 28)
                v = *(const uint4*)(in + (((size_t)b * 16 + cin) * 224 + gr) * 224 + c0);
            *(uint4*)(ls + (cin * 6 + r) * 232 + 8 * g) = v;
        }
    }
    for (int i = tid; i < 2304; i += 448) lw[i] = wq[i];
    if (tid < 16) lb[tid] = bias[tid];
    __syncthreads();
    // thread mapping: row(4) x cog(4) x colg(28)
    const int row = tid / 112, cog = (tid / 28) & 3, colg = tid % 28;
    const int c0g = colg * 8;
    float acc[8][4];
#pragma unroll
    for (int p = 0; p < 8; p++)
#pragma unroll
        for (int j = 0; j < 4; j++) acc[p][j] = 0.f;
#pragma unroll 4
    for (int cin = 0; cin < 16; cin++) {
        // per-cin weights for my 4 couts -> registers (b128 broadcast reads)
        float w[9][4];
#pragma unroll
        for (int t = 0; t < 9; t++) {
            float4 wv = *(const float4*)(lw + (cin * 9 + t) * 16 + cog * 4);
            w[t][0] = wv.x; w[t][1] = wv.y; w[t][2] = wv.z; w[t][3] = wv.w;
        }
#pragma unroll
        for (int ky = 0; ky < 3; ky++) {
            const short* rp = ls + (cin * 6 + row + ky) * 232;
            // xf[j] = x[c0g + j - 1] * ain, j = 0..9
            float xf[10];
            int2 lv = *(const int2*)(rp + c0g + 4);    // x[c0g-4..c0g-1]
            int4 mv = *(const int4*)(rp + c0g + 8);    // x[c0g..c0g+7]
            int  hv = *(const int*)(rp + c0g + 16);    // x[c0g+8], x[c0g+9]
            xf[0] = (float)((short)(lv.y >> 16)) * ain;
            xf[1] = (float)((short)(mv.x & 0xffff)) * ain;
            xf[2] = (float)((short)(mv.x >> 16)) * ain;
            xf[3] = (float)((short)(mv.y & 0xffff)) * ain;
            xf[4] = (float)((short)(mv.y >> 16)) * ain;
            xf[5] = (float)((short)(mv.z & 0xffff)) * ain;
            xf[6] = (float)((short)(mv.z >> 16)) * ain;
            xf[7] = (float)((short)(mv.w & 0xffff)) * ain;
            xf[8] = (float)((short)(mv.w >> 16)) * ain;
            xf[9] = (float)((short)(hv & 0xffff)) * ain;
#pragma unroll
            for (int kx = 0; kx < 3; kx++) {
#pragma unroll
                for (int p = 0; p < 8; p++) {
                    float xv = xf[p + kx];
#pragma unroll
                    for (int j = 0; j < 4; j++)
                        acc[p][j] = fmaf(xv, w[ky * 3 + kx][j], acc[p][j]);
                }
            }
        }
    }
    const int orow = r0 + row;
    if (!POOL) {
#pragma unroll
        for (int j = 0; j < 4; j++) {
            int ch = cog * 4 + j;
            float bb = lb[ch];
            int4 st;
            int pk[8];
#pragma unroll
            for (int p = 0; p < 8; p++) {
                float k = hgelu_code(acc[p][j] + bb, sc, three, six);
                pk[p] = (int)(short)fq_code(k * osc, anext) & 0xffff;
            }
            st.x = pk[0] | (pk[1] << 16);
            st.y = pk[2] | (pk[3] << 16);
            st.z = pk[4] | (pk[5] << 16);
            st.w = pk[6] | (pk[7] << 16);
            *(int4*)(out + (((size_t)b * 16 + ch) * 224 + orow) * 224 + c0g) = st;
        }
    } else {
        __syncthreads();               // done reading lw; reuse as pool scratch
        float* ps = lw;                // [448][4]
        float4 sv;
        float* s = (float*)&sv;
#pragma unroll
        for (int j = 0; j < 4; j++) {
            int ch = cog * 4 + j;
            float bb = lb[ch];
            float ksum = 0.f;
#pragma unroll
            for (int p = 0; p < 8; p++)
                ksum += hgelu_code(acc[p][j] + bb, sc, three, six);
            s[j] = ksum * osc;
        }
        *(float4*)(ps + tid * 4) = sv;
        __syncthreads();
        if (tid < 64) {
            int co = tid & 15, q = tid >> 4;
            int cg = co >> 2, j = co & 3;
            float t = 0.f;
#pragma unroll
            for (int cl = 0; cl < 28; cl++)
                t += ps[(q * 112 + cg * 28 + cl) * 4 + j];
            lred[q][co] = t;
        }
        __syncthreads();
        if (tid < 16) {
            float t = lred[0][tid] + lred[1][tid] + lred[2][tid] + lred[3][tid];
            partial[((size_t)b * 56 + rt) * 16 + tid] = t;
        }
    }
}

// ---------------- pool-reduce + quantized FC ----------------
__global__ __launch_bounds__(1024) void fc_kernel(const float* __restrict__ partial,
        const float* __restrict__ wq, const float* __restrict__ fb,
        const float* __restrict__ asc, float* __restrict__ out) {
    __shared__ float xq[64][16];
    const int t = threadIdx.x;
    const float a3 = asc[3];
    {
        int b = t >> 4, c = t & 15;
        const float* p = partial + ((size_t)b * 56) * 16 + c;
        float s = 0.f;
        for (int i = 0; i < 56; i++) s += p[i * 16];
        float pooled = s / 50176.0f;
        xq[b][c] = fq_code(pooled, a3) * a3;
    }
    __syncthreads();
    if (t < 640) {
        int b = t / 10, o = t - (t / 10) * 10;
        float s = 0.f;
#pragma unroll
        for (int c = 0; c < 16; c++) s += xq[b][c] * wq[o * 16 + c];
        out[t] = s + fb[o];
    }
}

extern "C" void kernel_launch(void* const* d_in, const int* in_sizes, int n_in,
                              void* d_out, int out_size, void* d_ws, size_t ws_size,
                              hipStream_t stream) {
    const float* x   = (const float*)d_in[0];
    const float* c1w = (const float*)d_in[1];
    const float* c1b = (const float*)d_in[2];
    const float* c2w = (const float*)d_in[3];
    const float* c2b = (const float*)d_in[4];
    const float* c3w = (const float*)d_in[5];
    const float* c3b = (const float*)d_in[6];
    const float* fcw = (const float*)d_in[7];
    const float* fcb = (const float*)d_in[8];
    const float* asc = (const float*)d_in[9];
    const float* shf = (const float*)d_in[10];

    char* ws = (char*)d_ws;
    size_t off = 0;
    auto alloc = [&](size_t bytes) -> void* {
        void* p = ws + off;
        off = (off + bytes + 255) & ~(size_t)255;
        return p;
    };
    float* wq1     = (float*)alloc(144 * 4);
    float* wq2     = (float*)alloc(2304 * 4);
    float* wq3     = (float*)alloc(2304 * 4);
    float* wqfc    = (float*)alloc(160 * 4);
    float* partial = (float*)alloc(64 * 56 * 16 * 4);
    short* actA    = (short*)alloc(51380224ull * 2);
    short* actB    = (short*)alloc(51380224ull * 2);

    prep_kernel<<<1, 256, 0, stream>>>(c1w, c2w, c3w, fcw, wq1, wq2, wq3, wqfc);
    conv1_kernel<<<1792, 448, 0, stream>>>(x, wq1, c1b, asc, shf, actA);
    conv16_kernel<false><<<3584, 448, 0, stream>>>(actA, wq2, c2b, asc, shf, actB, nullptr, 1, 1);
    conv16_kernel<true ><<<3584, 448, 0, stream>>>(actB, wq3, c3b, asc, shf, nullptr, partial, 2, 2);
    fc_kernel<<<1, 1024, 0, stream>>>(partial, wqfc, fcb, asc, (float*)d_out);
}

// Round 3
// 336.697 us; speedup vs baseline: 2.0641x; 1.7934x over previous
//
#include <hip/hip_runtime.h>
#include <math.h>

#define QMAXF 32767.0f

typedef short short8v __attribute__((ext_vector_type(8)));
typedef float f32x4 __attribute__((ext_vector_type(4)));

__device__ __forceinline__ float clampf(float v, float lo, float hi) {
    return fminf(fmaxf(v, lo), hi);
}
__device__ __forceinline__ float fq_code(float x, float s) {
    return clampf(rintf(x / s), -QMAXF, QMAXF);
}
__device__ __forceinline__ float hgelu_code(float y, float sc, float three, float six) {
    float xi    = clampf(rintf(y * sc), -32768.f, 32767.f);
    float slope = rintf(xi * 218.0f / 128.0f);
    float gate  = clampf(slope + three, 0.f, six);
    return clampf(rintf(xi * gate / six), -QMAXF, QMAXF);
}

// ---------------- weight prep ----------------
__device__ float block_scale(const float* w, int n, float* red) {
    float m = 0.f;
    for (int i = threadIdx.x; i < n; i += blockDim.x) m = fmaxf(m, fabsf(w[i]));
    red[threadIdx.x] = m; __syncthreads();
    for (int s = blockDim.x >> 1; s > 0; s >>= 1) {
        if ((int)threadIdx.x < s) red[threadIdx.x] = fmaxf(red[threadIdx.x], red[threadIdx.x + s]);
        __syncthreads();
    }
    float r = red[0]; __syncthreads();
    return fmaxf(r / QMAXF, 1e-8f);
}

// wq2b/wq3b layout: [tap 9][kblock 4][cout 16][8] bf16 (ushort)
// kblock 0: wh cin0-7, 1: wh cin8-15, 2: wl cin0-7, 3: wl cin8-15
__global__ void prep_kernel(const float* __restrict__ w1, const float* __restrict__ w2,
                            const float* __restrict__ w3, const float* __restrict__ wfc,
                            float* __restrict__ wq1, ushort* __restrict__ wq2b,
                            ushort* __restrict__ wq3b, float* __restrict__ wqfc,
                            float* __restrict__ wsb) {
    __shared__ float red[256];
    float s = block_scale(w1, 144, red);   // [16][1][3][3] -> [tap][16] fp32
    for (int i = threadIdx.x; i < 144; i += 256) {
        int co = i / 9, r = i % 9;
        wq1[r * 16 + co] = fq_code(w1[i], s) * s;
    }
    __syncthreads();
    s = block_scale(w2, 2304, red);
    if (threadIdx.x == 0) wsb[0] = s;
    for (int i = threadIdx.x; i < 2304; i += 256) {
        int co = i / 144, rem = i % 144, cin = rem / 9, t = rem % 9;
        int wc = (int)fq_code(w2[i], s);
        uint bh = __float_as_uint((float)(wc & ~127)) >> 16;
        uint bl = __float_as_uint((float)(wc & 127)) >> 16;
        int kb = cin >> 3, j = cin & 7;
        wq2b[((t * 4 + kb) * 16 + co) * 8 + j]     = (ushort)bh;
        wq2b[((t * 4 + 2 + kb) * 16 + co) * 8 + j] = (ushort)bl;
    }
    __syncthreads();
    s = block_scale(w3, 2304, red);
    if (threadIdx.x == 0) wsb[1] = s;
    for (int i = threadIdx.x; i < 2304; i += 256) {
        int co = i / 144, rem = i % 144, cin = rem / 9, t = rem % 9;
        int wc = (int)fq_code(w3[i], s);
        uint bh = __float_as_uint((float)(wc & ~127)) >> 16;
        uint bl = __float_as_uint((float)(wc & 127)) >> 16;
        int kb = cin >> 3, j = cin & 7;
        wq3b[((t * 4 + kb) * 16 + co) * 8 + j]     = (ushort)bh;
        wq3b[((t * 4 + 2 + kb) * 16 + co) * 8 + j] = (ushort)bl;
    }
    __syncthreads();
    s = block_scale(wfc, 160, red);
    for (int i = threadIdx.x; i < 160; i += 256) wqfc[i] = fq_code(wfc[i], s) * s;
}

// ---------------- conv1: 1->16 ch (VALU), outputs NHWC int16 codes ----------------
__global__ __launch_bounds__(448) void conv1_kernel(const float* __restrict__ x,
        const float* __restrict__ wq, const float* __restrict__ bias,
        const float* __restrict__ asc, const float* __restrict__ shf,
        ushort* __restrict__ out) {
    const int bid = blockIdx.x;
    const int b = bid / 28, rt = bid % 28, r0 = rt * 8;
    const int tid = threadIdx.x;
    __shared__ alignas(16) short lx[10][224];
    __shared__ alignas(16) float lw[144];
    __shared__ float lb[16];
    const float a0 = asc[0], a1 = asc[1];
    const float sh = clampf(rintf(shf[0]), 4.f, 12.f);
    const float sc = exp2f(sh), osc = exp2f(-sh);
    const float three = 3.f * sc, six = 6.f * sc;
    const float* xb = x + (size_t)b * 50176;
    for (int i = tid; i < 2240; i += 448) {
        int r = i / 224, c = i - r * 224, sr = r0 - 1 + r;
        float v = (sr >= 0 && sr < 224) ? xb[sr * 224 + c] : 0.f;
        lx[r][c] = (short)fq_code(v, a0);
    }
    for (int i = tid; i < 144; i += 448) lw[i] = wq[i];
    if (tid < 16) lb[tid] = bias[tid];
    __syncthreads();
    const int myrow = tid / 56, p0 = (tid - myrow * 56) * 4;
    float acc[4][16];
#pragma unroll
    for (int px = 0; px < 4; px++)
#pragma unroll
        for (int co = 0; co < 16; co++) acc[px][co] = 0.f;
#pragma unroll
    for (int ky = 0; ky < 3; ky++) {
        const short* rp = &lx[myrow + ky][0];
        float xf[6];
        short4 v = *(const short4*)(rp + p0);
        xf[1] = (float)v.x * a0; xf[2] = (float)v.y * a0;
        xf[3] = (float)v.z * a0; xf[4] = (float)v.w * a0;
        xf[0] = (p0 > 0)   ? (float)rp[p0 - 1] * a0 : 0.f;
        xf[5] = (p0 < 220) ? (float)rp[p0 + 4] * a0 : 0.f;
#pragma unroll
        for (int kx = 0; kx < 3; kx++) {
            const float* wp = &lw[(ky * 3 + kx) * 16];
#pragma unroll
            for (int px = 0; px < 4; px++) {
                float xv = xf[px + kx];
#pragma unroll
                for (int co = 0; co < 16; co++) acc[px][co] = fmaf(xv, wp[co], acc[px][co]);
            }
        }
    }
    const int orow = r0 + myrow;
    const size_t obase = ((size_t)b * 224 + orow) * 224 + p0;   // pixel index
#pragma unroll
    for (int px = 0; px < 4; px++) {
        uint pk[8];
#pragma unroll
        for (int co = 0; co < 16; co++) {
            float k = hgelu_code(acc[px][co] + lb[co], sc, three, six);
            int cd = (int)fq_code(k * osc, a1);
            if (co & 1) pk[co >> 1] |= ((uint)cd & 0xffffu) << 16;
            else        pk[co >> 1] = (uint)cd & 0xffffu;
        }
        uint4* dst = (uint4*)(out + (obase + px) * 16);
        dst[0] = make_uint4(pk[0], pk[1], pk[2], pk[3]);
        dst[1] = make_uint4(pk[4], pk[5], pk[6], pk[7]);
    }
}

// ---------------- conv2/conv3: MFMA implicit GEMM ----------------
// Block: 4 output rows x 112 cols (NHWC), 4 waves; wave w owns output row r0+w.
// LDS x: 6 rows x 114 entries, entry = 64B = 4 chunks of 8 bf16:
//   chunk0 xh cin0-7, 1 xh cin8-15, 2 xl cin0-7, 3 xl cin8-15; slot = (chunk+rot(e))&3.
template <bool POOL>
__global__ __launch_bounds__(256, 3) void conv16_kernel(
        const ushort* __restrict__ in, const ushort* __restrict__ wq,
        const float* __restrict__ bias, const float* __restrict__ asc,
        const float* __restrict__ shf, const float* __restrict__ wsb,
        ushort* __restrict__ out, float* __restrict__ partial,
        int aidx, int sidx, int widx) {
    const int bid = blockIdx.x;
    const int b = bid / 112, rem = bid % 112, rg = rem >> 1, ch = rem & 1;
    const int r0 = rg * 4, c0 = ch * 112;
    const int tid = threadIdx.x;
    const int l = tid & 63, w = tid >> 6;
    const int l15 = l & 15, lk = l >> 4;

    __shared__ alignas(16) ushort lsx[684 * 32];        // 43776 B
    __shared__ alignas(16) ushort swr[4][16 * 24];      //  3072 B (per-wave transpose)
    __shared__ float lred[4][16];

    const float ain = asc[aidx];
    const float anext = asc[aidx + 1];
    const float wsc = wsb[widx];
    const float gscale = ain * wsc;
    const float sh = clampf(rintf(shf[sidx]), 4.f, 12.f);
    const float sc = exp2f(sh), osc = exp2f(-sh);
    const float three = 3.f * sc, six = 6.f * sc;
    const float breg = bias[l15];

    // ---- B fragments into registers: pass1 [wh|wl], pass2 [wl|wh] ----
    short8v B1[9], B2[9];
#pragma unroll
    for (int t = 0; t < 9; t++) {
        B1[t] = *(const short8v*)(wq + ((t * 4 + lk) * 16 + l15) * 8);
        B2[t] = *(const short8v*)(wq + ((t * 4 + (lk ^ 2)) * 16 + l15) * 8);
    }

    // ---- stage x tile: 6 rows x 114 cols, split codes into bf16 hi/lo ----
#pragma unroll
    for (int it = 0; it < 3; it++) {
        int e = tid + it * 256;
        if (e < 684) {
            int r = e / 114, cc = e - r * 114;
            int ir = r0 - 1 + r, ic = c0 - 1 + cc;
            uint4 va = make_uint4(0u, 0u, 0u, 0u), vb = make_uint4(0u, 0u, 0u, 0u);
            if ((unsigned)ir < 224u && (unsigned)ic < 224u) {
                const uint4* src = (const uint4*)(in + (((size_t)b * 224 + ir) * 224 + ic) * 16);
                va = src[0]; vb = src[1];
            }
            uint uu[8] = {va.x, va.y, va.z, va.w, vb.x, vb.y, vb.z, vb.w};
            uint hi[8], lo[8];
#pragma unroll
            for (int i = 0; i < 8; i++) {
                int e0 = (int)(short)(uu[i] & 0xffffu);
                int e1 = (int)(short)(uu[i] >> 16);
                uint bh0 = __float_as_uint((float)(e0 & ~127)) >> 16;
                uint bl0 = __float_as_uint((float)(e0 & 127)) >> 16;
                uint bh1 = __float_as_uint((float)(e1 & ~127)) >> 16;
                uint bl1 = __float_as_uint((float)(e1 & 127)) >> 16;
                hi[i] = bh0 | (bh1 << 16);
                lo[i] = bl0 | (bl1 << 16);
            }
            int rot = (e + (e >> 2)) & 3;
            ushort* eb = lsx + e * 32;
            *(uint4*)(eb + ((0 + rot) & 3) * 8) = make_uint4(hi[0], hi[1], hi[2], hi[3]);
            *(uint4*)(eb + ((1 + rot) & 3) * 8) = make_uint4(hi[4], hi[5], hi[6], hi[7]);
            *(uint4*)(eb + ((2 + rot) & 3) * 8) = make_uint4(lo[0], lo[1], lo[2], lo[3]);
            *(uint4*)(eb + ((3 + rot) & 3) * 8) = make_uint4(lo[4], lo[5], lo[6], lo[7]);
        }
    }
    __syncthreads();

    float wsum = 0.f;
    const int orow = r0 + w;
    for (int cg = 0; cg < 7; cg++) {
        f32x4 acc0 = {0.f, 0.f, 0.f, 0.f}, acc1 = {0.f, 0.f, 0.f, 0.f};
        const int cbase = cg * 16 + l15;
#pragma unroll
        for (int ky = 0; ky < 3; ky++) {
#pragma unroll
            for (int kx = 0; kx < 3; kx++) {
                int e = (w + ky) * 114 + cbase + kx;
                int slot = (lk + e + (e >> 2)) & 3;
                short8v a = *(const short8v*)(lsx + e * 32 + slot * 8);
                int t = ky * 3 + kx;
                if (t & 1) {
                    acc1 = __builtin_amdgcn_mfma_f32_16x16x32_bf16(a, B1[t], acc1, 0, 0, 0);
                    acc1 = __builtin_amdgcn_mfma_f32_16x16x32_bf16(a, B2[t], acc1, 0, 0, 0);
                } else {
                    acc0 = __builtin_amdgcn_mfma_f32_16x16x32_bf16(a, B1[t], acc0, 0, 0, 0);
                    acc0 = __builtin_amdgcn_mfma_f32_16x16x32_bf16(a, B2[t], acc0, 0, 0, 0);
                }
            }
        }
        if (!POOL) {
            ushort codes[4];
#pragma unroll
            for (int r = 0; r < 4; r++) {
                float y = (acc0[r] + acc1[r]) * gscale + breg;
                float k = hgelu_code(y, sc, three, six);
                codes[r] = (ushort)(short)(int)fq_code(k * osc, anext);
            }
#pragma unroll
            for (int r = 0; r < 4; r++)
                swr[w][(lk * 4 + r) * 24 + l15] = codes[r];
            asm volatile("s_waitcnt lgkmcnt(0)" ::: "memory");
            if (l < 32) {
                int px = l >> 1, half = l & 1;
                uint4 v = *(const uint4*)(&swr[w][px * 24 + half * 8]);
                *(uint4*)(out + (((size_t)b * 224 + orow) * 224 + (c0 + cg * 16 + px)) * 16 + half * 8) = v;
            }
        } else {
            float s = 0.f;
#pragma unroll
            for (int r = 0; r < 4; r++) {
                float y = (acc0[r] + acc1[r]) * gscale + breg;
                s += hgelu_code(y, sc, three, six);
            }
            s *= osc;
            s += __shfl_xor(s, 16);
            s += __shfl_xor(s, 32);
            wsum += s;
        }
    }
    if (POOL) {
        if (l < 16) lred[w][l] = wsum;
        __syncthreads();
        if (tid < 16) {
            partial[((size_t)b * 112 + rem) * 16 + tid] =
                lred[0][tid] + lred[1][tid] + lred[2][tid] + lred[3][tid];
        }
    }
}

// ---------------- pool-reduce + quantized FC ----------------
__global__ __launch_bounds__(1024) void fc_kernel(const float* __restrict__ partial,
        const float* __restrict__ wq, const float* __restrict__ fb,
        const float* __restrict__ asc, float* __restrict__ out) {
    __shared__ float xq[64][16];
    const int t = threadIdx.x;
    const float a3 = asc[3];
    {
        int b = t >> 4, c = t & 15;
        const float* p = partial + ((size_t)b * 112) * 16 + c;
        float s = 0.f;
        for (int i = 0; i < 112; i++) s += p[i * 16];
        float pooled = s / 50176.0f;
        xq[b][c] = fq_code(pooled, a3) * a3;
    }
    __syncthreads();
    if (t < 640) {
        int b = t / 10, o = t - (t / 10) * 10;
        float s = 0.f;
#pragma unroll
        for (int c = 0; c < 16; c++) s += xq[b][c] * wq[o * 16 + c];
        out[t] = s + fb[o];
    }
}

extern "C" void kernel_launch(void* const* d_in, const int* in_sizes, int n_in,
                              void* d_out, int out_size, void* d_ws, size_t ws_size,
                              hipStream_t stream) {
    const float* x   = (const float*)d_in[0];
    const float* c1w = (const float*)d_in[1];
    const float* c1b = (const float*)d_in[2];
    const float* c2w = (const float*)d_in[3];
    const float* c2b = (const float*)d_in[4];
    const float* c3w = (const float*)d_in[5];
    const float* c3b = (const float*)d_in[6];
    const float* fcw = (const float*)d_in[7];
    const float* fcb = (const float*)d_in[8];
    const float* asc = (const float*)d_in[9];
    const float* shf = (const float*)d_in[10];

    char* ws = (char*)d_ws;
    size_t off = 0;
    auto alloc = [&](size_t bytes) -> void* {
        void* p = ws + off;
        off = (off + bytes + 255) & ~(size_t)255;
        return p;
    };
    float*  wq1     = (float*)alloc(144 * 4);
    ushort* wq2b    = (ushort*)alloc(4608 * 2);
    ushort* wq3b    = (ushort*)alloc(4608 * 2);
    float*  wqfc    = (float*)alloc(160 * 4);
    float*  wsb     = (float*)alloc(4 * 4);
    float*  partial = (float*)alloc(64 * 112 * 16 * 4);
    ushort* actA    = (ushort*)alloc(51380224ull * 2);
    ushort* actB    = (ushort*)alloc(51380224ull * 2);

    prep_kernel<<<1, 256, 0, stream>>>(c1w, c2w, c3w, fcw, wq1, wq2b, wq3b, wqfc, wsb);
    conv1_kernel<<<1792, 448, 0, stream>>>(x, wq1, c1b, asc, shf, actA);
    conv16_kernel<false><<<7168, 256, 0, stream>>>(actA, wq2b, c2b, asc, shf, wsb,
                                                   actB, nullptr, 1, 1, 0);
    conv16_kernel<true ><<<7168, 256, 0, stream>>>(actB, wq3b, c3b, asc, shf, wsb,
                                                   nullptr, partial, 2, 2, 1);
    fc_kernel<<<1, 1024, 0, stream>>>(partial, wqfc, fcb, asc, (float*)d_out);
}

// Round 4
// 244.931 us; speedup vs baseline: 2.8375x; 1.3747x over previous
//
#include <hip/hip_runtime.h>
#include <math.h>

#define QMAXF 32767.0f

typedef short short8v __attribute__((ext_vector_type(8)));
typedef float f32x4 __attribute__((ext_vector_type(4)));

__device__ __forceinline__ float clampf(float v, float lo, float hi) {
    return fminf(fmaxf(v, lo), hi);
}
__device__ __forceinline__ float fq_code(float x, float s) {
    return clampf(rintf(x / s), -QMAXF, QMAXF);
}

// ---------------- weight prep ----------------
__device__ float block_scale(const float* w, int n, float* red) {
    float m = 0.f;
    for (int i = threadIdx.x; i < n; i += blockDim.x) m = fmaxf(m, fabsf(w[i]));
    red[threadIdx.x] = m; __syncthreads();
    for (int s = blockDim.x >> 1; s > 0; s >>= 1) {
        if ((int)threadIdx.x < s) red[threadIdx.x] = fmaxf(red[threadIdx.x], red[threadIdx.x + s]);
        __syncthreads();
    }
    float r = red[0]; __syncthreads();
    return fmaxf(r / QMAXF, 1e-8f);
}

// wq2b/wq3b layout: [tap 9][kblock 4][cout 16][8] bf16 (ushort)
// kblock 0: wh cin0-7, 1: wh cin8-15, 2: wl cin0-7, 3: wl cin8-15
__global__ void prep_kernel(const float* __restrict__ w1, const float* __restrict__ w2,
                            const float* __restrict__ w3, const float* __restrict__ wfc,
                            const float* __restrict__ asc,
                            float* __restrict__ wq1, ushort* __restrict__ wq2b,
                            ushort* __restrict__ wq3b, float* __restrict__ wqfc,
                            float* __restrict__ wsb) {
    __shared__ float red[256];
    float s = block_scale(w1, 144, red);   // [16][1][3][3] -> [tap][16] fp32, a0 folded in
    float a0 = asc[0];
    for (int i = threadIdx.x; i < 144; i += 256) {
        int co = i / 9, r = i % 9;
        wq1[r * 16 + co] = fq_code(w1[i], s) * s * a0;
    }
    __syncthreads();
    s = block_scale(w2, 2304, red);
    if (threadIdx.x == 0) wsb[0] = s;
    for (int i = threadIdx.x; i < 2304; i += 256) {
        int co = i / 144, rem = i % 144, cin = rem / 9, t = rem % 9;
        int wc = (int)fq_code(w2[i], s);
        uint bh = __float_as_uint((float)(wc & ~127)) >> 16;
        uint bl = __float_as_uint((float)(wc & 127)) >> 16;
        int kb = cin >> 3, j = cin & 7;
        wq2b[((t * 4 + kb) * 16 + co) * 8 + j]     = (ushort)bh;
        wq2b[((t * 4 + 2 + kb) * 16 + co) * 8 + j] = (ushort)bl;
    }
    __syncthreads();
    s = block_scale(w3, 2304, red);
    if (threadIdx.x == 0) wsb[1] = s;
    for (int i = threadIdx.x; i < 2304; i += 256) {
        int co = i / 144, rem = i % 144, cin = rem / 9, t = rem % 9;
        int wc = (int)fq_code(w3[i], s);
        uint bh = __float_as_uint((float)(wc & ~127)) >> 16;
        uint bl = __float_as_uint((float)(wc & 127)) >> 16;
        int kb = cin >> 3, j = cin & 7;
        wq3b[((t * 4 + kb) * 16 + co) * 8 + j]     = (ushort)bh;
        wq3b[((t * 4 + 2 + kb) * 16 + co) * 8 + j] = (ushort)bl;
    }
    __syncthreads();
    s = block_scale(wfc, 160, red);
    for (int i = threadIdx.x; i < 160; i += 256) wqfc[i] = fq_code(wfc[i], s) * s;
}

// ---------------- conv1: 1->16 ch (VALU), outputs NHWC int16 codes ----------------
__global__ __launch_bounds__(448) void conv1_kernel(const float* __restrict__ x,
        const float* __restrict__ wq, const float* __restrict__ bias,
        const float* __restrict__ asc, const float* __restrict__ shf,
        ushort* __restrict__ out) {
    const int bid = blockIdx.x;
    const int b = bid / 28, rt = bid % 28, r0 = rt * 8;
    const int tid = threadIdx.x;
    __shared__ alignas(16) short lx[10][224];
    __shared__ alignas(16) float lw[144];
    __shared__ float lbsc[16];
    const float a0 = asc[0], a1 = asc[1];
    const float r0a = 1.0f / a0;
    const float sh = clampf(rintf(shf[0]), 4.f, 12.f);
    const float sc = exp2f(sh), osc = exp2f(-sh);
    const float three = 3.f * sc, six = 6.f * sc;
    const float r6 = 1.0f / six;
    const float rq1 = osc / a1;
    const float* xb = x + (size_t)b * 50176;
    for (int i = tid; i < 2240; i += 448) {
        int r = i / 224, c = i - r * 224, sr = r0 - 1 + r;
        float v = (sr >= 0 && sr < 224) ? xb[sr * 224 + c] : 0.f;
        lx[r][c] = (short)clampf(rintf(v * r0a), -QMAXF, QMAXF);
    }
    for (int i = tid; i < 144; i += 448) lw[i] = wq[i];
    if (tid < 16) lbsc[tid] = bias[tid] * sc;
    __syncthreads();
    const int myrow = tid / 56, p0 = (tid - myrow * 56) * 4;
    float acc[4][16];
#pragma unroll
    for (int px = 0; px < 4; px++)
#pragma unroll
        for (int co = 0; co < 16; co++) acc[px][co] = 0.f;
#pragma unroll
    for (int ky = 0; ky < 3; ky++) {
        const short* rp = &lx[myrow + ky][0];
        float xf[6];
        short4 v = *(const short4*)(rp + p0);
        xf[1] = (float)v.x; xf[2] = (float)v.y;
        xf[3] = (float)v.z; xf[4] = (float)v.w;
        xf[0] = (p0 > 0)   ? (float)rp[p0 - 1] : 0.f;
        xf[5] = (p0 < 220) ? (float)rp[p0 + 4] : 0.f;
#pragma unroll
        for (int kx = 0; kx < 3; kx++) {
            const float* wp = &lw[(ky * 3 + kx) * 16];
#pragma unroll
            for (int px = 0; px < 4; px++) {
                float xv = xf[px + kx];
#pragma unroll
                for (int co = 0; co < 16; co++) acc[px][co] = fmaf(xv, wp[co], acc[px][co]);
            }
        }
    }
    const int orow = r0 + myrow;
    const size_t obase = ((size_t)b * 224 + orow) * 224 + p0;   // pixel index
#pragma unroll
    for (int px = 0; px < 4; px++) {
        uint pk[8];
#pragma unroll
        for (int co = 0; co < 16; co++) {
            float xi = clampf(rintf(fmaf(acc[px][co], sc, lbsc[co])), -32768.f, 32767.f);
            float slope = rintf(xi * 1.703125f);
            float gate = clampf(slope + three, 0.f, six);
            float k = clampf(rintf(xi * gate * r6), -QMAXF, QMAXF);
            int cd = (int)clampf(rintf(k * rq1), -QMAXF, QMAXF);
            if (co & 1) pk[co >> 1] |= ((uint)cd & 0xffffu) << 16;
            else        pk[co >> 1] = (uint)cd & 0xffffu;
        }
        uint4* dst = (uint4*)(out + (obase + px) * 16);
        dst[0] = make_uint4(pk[0], pk[1], pk[2], pk[3]);
        dst[1] = make_uint4(pk[4], pk[5], pk[6], pk[7]);
    }
}

// ---------------- conv2/conv3: MFMA implicit GEMM (D = W * X) ----------------
// Block: 4 output rows x 112 cols (NHWC). Wave w -> row r0+w. Lane: l15 = pixel col,
// lk = K-chunk; D regs = 4 consecutive couts (lk*4+r).
// LDS x: entries e = row*114 + col; entry = 64B = 4 chunks of 8 bf16
// (0: xh cin0-7, 1: xh cin8-15, 2: xl cin0-7, 3: xl cin8-15); chunk c at slot c^((e>>1)&3).
template <bool POOL>
__global__ __launch_bounds__(256, 3) void conv16_kernel(
        const ushort* __restrict__ in, const ushort* __restrict__ wq,
        const float* __restrict__ bias, const float* __restrict__ asc,
        const float* __restrict__ shf, const float* __restrict__ wsb,
        ushort* __restrict__ out, float* __restrict__ partial,
        int aidx, int sidx, int widx) {
    const int bid = blockIdx.x;
    const int b = bid / 112, rem = bid % 112, rg = rem >> 1, ch = rem & 1;
    const int r0 = rg * 4, c0 = ch * 112;
    const int tid = threadIdx.x;
    const int l = tid & 63, w = tid >> 6;
    const int l15 = l & 15, lk = l >> 4;

    __shared__ alignas(16) ushort lsx[684 * 32];        // 43776 B
    __shared__ float lred[4][16];

    const float ain = asc[aidx];
    const float anext = asc[aidx + 1];
    const float wsc = wsb[widx];
    const float sh = clampf(rintf(shf[sidx]), 4.f, 12.f);
    const float sc = exp2f(sh), osc = exp2f(-sh);
    const float three = 3.f * sc, six = 6.f * sc;
    const float gs2 = (ain * wsc) * sc;
    const float r6 = 1.0f / six;
    const float rq = osc / anext;
    float bsc[4];
#pragma unroll
    for (int r = 0; r < 4; r++) bsc[r] = bias[lk * 4 + r] * sc;

    // ---- W fragments (A operand): pass1 [wh|wl], pass2 [wl|wh] ----
    short8v B1[9], B2[9];
#pragma unroll
    for (int t = 0; t < 9; t++) {
        B1[t] = *(const short8v*)(wq + ((t * 4 + lk) * 16 + l15) * 8);
        B2[t] = *(const short8v*)(wq + ((t * 4 + (lk ^ 2)) * 16 + l15) * 8);
    }

    // ---- stage x tile: 6 rows x 114 cols, split codes into bf16 hi/lo ----
#pragma unroll
    for (int it = 0; it < 3; it++) {
        int e = tid + it * 256;
        if (e < 684) {
            int r = e / 114, cc = e - r * 114;
            int ir = r0 - 1 + r, ic = c0 - 1 + cc;
            uint4 va = make_uint4(0u, 0u, 0u, 0u), vb = make_uint4(0u, 0u, 0u, 0u);
            if ((unsigned)ir < 224u && (unsigned)ic < 224u) {
                const uint4* src = (const uint4*)(in + (((size_t)b * 224 + ir) * 224 + ic) * 16);
                va = src[0]; vb = src[1];
            }
            uint uu[8] = {va.x, va.y, va.z, va.w, vb.x, vb.y, vb.z, vb.w};
            uint hi[8], lo[8];
#pragma unroll
            for (int i = 0; i < 8; i++) {
                int e0 = (int)(short)(uu[i] & 0xffffu);
                int e1 = (int)uu[i] >> 16;
                int l0 = e0 & 127, l1 = e1 & 127;
                uint fh0 = __float_as_uint((float)(e0 - l0));
                uint fh1 = __float_as_uint((float)(e1 - l1));
                uint fl0 = __float_as_uint((float)l0);
                uint fl1 = __float_as_uint((float)l1);
                hi[i] = (fh0 >> 16) | (fh1 & 0xffff0000u);
                lo[i] = (fl0 >> 16) | (fl1 & 0xffff0000u);
            }
            int rot = (e >> 1) & 3;
            ushort* eb = lsx + e * 32;
            *(uint4*)(eb + ((0 ^ rot) << 3)) = make_uint4(hi[0], hi[1], hi[2], hi[3]);
            *(uint4*)(eb + ((1 ^ rot) << 3)) = make_uint4(hi[4], hi[5], hi[6], hi[7]);
            *(uint4*)(eb + ((2 ^ rot) << 3)) = make_uint4(lo[0], lo[1], lo[2], lo[3]);
            *(uint4*)(eb + ((3 ^ rot) << 3)) = make_uint4(lo[4], lo[5], lo[6], lo[7]);
        }
    }
    __syncthreads();

    // ---- per-lane swizzled base pointers: affine period 8 in entry index ----
    const ushort* Ab[7];
#pragma unroll
    for (int m = 0; m < 7; m++) {
        int e = w * 114 + l15 + m;
        Ab[m] = lsx + e * 32 + ((lk ^ ((e >> 1) & 3)) << 3);
    }

    float wsum[4] = {0.f, 0.f, 0.f, 0.f};
    const int orow = r0 + w;
    ushort* opb = out + (((size_t)b * 224 + orow) * 224 + c0 + l15) * 16 + lk * 4;
#pragma unroll
    for (int cg = 0; cg < 7; cg++) {
        f32x4 acc0 = {0.f, 0.f, 0.f, 0.f}, acc1 = {0.f, 0.f, 0.f, 0.f};
#pragma unroll
        for (int ky = 0; ky < 3; ky++) {
#pragma unroll
            for (int kx = 0; kx < 3; kx++) {
                // entry offset from base: 3584*ky + 512*cg shorts (compile-time)
                short8v a = *(const short8v*)(Ab[2 * ky + kx] + 3584 * ky + 512 * cg);
                int t = ky * 3 + kx;
                if (t & 1) {
                    acc1 = __builtin_amdgcn_mfma_f32_16x16x32_bf16(B1[t], a, acc1, 0, 0, 0);
                    acc1 = __builtin_amdgcn_mfma_f32_16x16x32_bf16(B2[t], a, acc1, 0, 0, 0);
                } else {
                    acc0 = __builtin_amdgcn_mfma_f32_16x16x32_bf16(B1[t], a, acc0, 0, 0, 0);
                    acc0 = __builtin_amdgcn_mfma_f32_16x16x32_bf16(B2[t], a, acc0, 0, 0, 0);
                }
            }
        }
        if (!POOL) {
            int cd[4];
#pragma unroll
            for (int r = 0; r < 4; r++) {
                float s = acc0[r] + acc1[r];
                float xi = clampf(rintf(fmaf(s, gs2, bsc[r])), -32768.f, 32767.f);
                float slope = rintf(xi * 1.703125f);
                float gate = clampf(slope + three, 0.f, six);
                float k = clampf(rintf(xi * gate * r6), -QMAXF, QMAXF);
                cd[r] = (int)clampf(rintf(k * rq), -QMAXF, QMAXF);
            }
            uint2 st;
            st.x = ((uint)cd[0] & 0xffffu) | ((uint)cd[1] << 16);
            st.y = ((uint)cd[2] & 0xffffu) | ((uint)cd[3] << 16);
            *(uint2*)(opb + cg * 256) = st;
        } else {
#pragma unroll
            for (int r = 0; r < 4; r++) {
                float s = acc0[r] + acc1[r];
                float xi = clampf(rintf(fmaf(s, gs2, bsc[r])), -32768.f, 32767.f);
                float slope = rintf(xi * 1.703125f);
                float gate = clampf(slope + three, 0.f, six);
                float k = clampf(rintf(xi * gate * r6), -QMAXF, QMAXF);
                wsum[r] += k;
            }
        }
    }
    if (POOL) {
#pragma unroll
        for (int r = 0; r < 4; r++) {
            float v = wsum[r] * osc;
            v += __shfl_xor(v, 1);
            v += __shfl_xor(v, 2);
            v += __shfl_xor(v, 4);
            v += __shfl_xor(v, 8);
            if (l15 == 0) lred[w][lk * 4 + r] = v;
        }
        __syncthreads();
        if (tid < 16) {
            partial[((size_t)b * 112 + rem) * 16 + tid] =
                lred[0][tid] + lred[1][tid] + lred[2][tid] + lred[3][tid];
        }
    }
}

// ---------------- pool-reduce + quantized FC (exact divisions; tiny) ----------------
__global__ __launch_bounds__(1024) void fc_kernel(const float* __restrict__ partial,
        const float* __restrict__ wq, const float* __restrict__ fb,
        const float* __restrict__ asc, float* __restrict__ out) {
    __shared__ float xq[64][16];
    const int t = threadIdx.x;
    const float a3 = asc[3];
    {
        int b = t >> 4, c = t & 15;
        const float* p = partial + ((size_t)b * 112) * 16 + c;
        float s = 0.f;
        for (int i = 0; i < 112; i++) s += p[i * 16];
        float pooled = s / 50176.0f;
        xq[b][c] = fq_code(pooled, a3) * a3;
    }
    __syncthreads();
    if (t < 640) {
        int b = t / 10, o = t - (t / 10) * 10;
        float s = 0.f;
#pragma unroll
        for (int c = 0; c < 16; c++) s += xq[b][c] * wq[o * 16 + c];
        out[t] = s + fb[o];
    }
}

extern "C" void kernel_launch(void* const* d_in, const int* in_sizes, int n_in,
                              void* d_out, int out_size, void* d_ws, size_t ws_size,
                              hipStream_t stream) {
    const float* x   = (const float*)d_in[0];
    const float* c1w = (const float*)d_in[1];
    const float* c1b = (const float*)d_in[2];
    const float* c2w = (const float*)d_in[3];
    const float* c2b = (const float*)d_in[4];
    const float* c3w = (const float*)d_in[5];
    const float* c3b = (const float*)d_in[6];
    const float* fcw = (const float*)d_in[7];
    const float* fcb = (const float*)d_in[8];
    const float* asc = (const float*)d_in[9];
    const float* shf = (const float*)d_in[10];

    char* ws = (char*)d_ws;
    size_t off = 0;
    auto alloc = [&](size_t bytes) -> void* {
        void* p = ws + off;
        off = (off + bytes + 255) & ~(size_t)255;
        return p;
    };
    float*  wq1     = (float*)alloc(144 * 4);
    ushort* wq2b    = (ushort*)alloc(4608 * 2);
    ushort* wq3b    = (ushort*)alloc(4608 * 2);
    float*  wqfc    = (float*)alloc(160 * 4);
    float*  wsb     = (float*)alloc(4 * 4);
    float*  partial = (float*)alloc(64 * 112 * 16 * 4);
    ushort* actA    = (ushort*)alloc(51380224ull * 2);
    ushort* actB    = (ushort*)alloc(51380224ull * 2);

    prep_kernel<<<1, 256, 0, stream>>>(c1w, c2w, c3w, fcw, asc, wq1, wq2b, wq3b, wqfc, wsb);
    conv1_kernel<<<1792, 448, 0, stream>>>(x, wq1, c1b, asc, shf, actA);
    conv16_kernel<false><<<7168, 256, 0, stream>>>(actA, wq2b, c2b, asc, shf, wsb,
                                                   actB, nullptr, 1, 1, 0);
    conv16_kernel<true ><<<7168, 256, 0, stream>>>(actB, wq3b, c3b, asc, shf, wsb,
                                                   nullptr, partial, 2, 2, 1);
    fc_kernel<<<1, 1024, 0, stream>>>(partial, wqfc, fcb, asc, (float*)d_out);
}